// Round 3
// baseline (538.152 us; speedup 1.0000x reference)
//
#include <hip/hip_runtime.h>

typedef unsigned short u16;
typedef unsigned int u32;
typedef u16 us8 __attribute__((ext_vector_type(8)));
typedef __bf16 bf16x8 __attribute__((ext_vector_type(8)));
typedef float f32x4 __attribute__((ext_vector_type(4)));

constexpr int kE = 8;
constexpr int kHID = 2048;    // K of GEMM1, N of GEMM2
constexpr int kINTER = 1408;  // N of GEMM1, K of GEMM2
constexpr int kTOT = 8192;

// fp32 -> bf16 round-to-nearest-even
static __device__ __forceinline__ u16 f2bf(float f) {
  u32 u = __float_as_uint(f);
  u32 r = (u + 0x7fffu + ((u >> 16) & 1u)) >> 16;
  return (u16)r;
}

// async global->LDS, 16B per lane; LDS dest = wave-uniform base + lane*16
static __device__ __forceinline__ void gll16(const u16* g, u16* l) {
  __builtin_amdgcn_global_load_lds(
      (const __attribute__((address_space(1))) u32*)g,
      (__attribute__((address_space(3))) u32*)l, 16, 0, 0);
}

// ---------------- pre-pass: X fp32 -> bf16 ----------------
__global__ void conv_bf16(const float* __restrict__ x, u16* __restrict__ o) {
  size_t i = ((size_t)blockIdx.x * 256 + threadIdx.x) * 8;
  const float4* p = (const float4*)(x + i);
  float4 f0 = p[0], f1 = p[1];
  us8 v;
  v[0] = f2bf(f0.x); v[1] = f2bf(f0.y); v[2] = f2bf(f0.z); v[3] = f2bf(f0.w);
  v[4] = f2bf(f1.x); v[5] = f2bf(f1.y); v[6] = f2bf(f1.z); v[7] = f2bf(f1.w);
  *(us8*)(o + i) = v;
}

// ---------------- pre-pass: W[e][K][N] fp32 -> Wt[e][N][K] bf16 ----------------
__global__ void transp_bf16(const float* __restrict__ w, u16* __restrict__ wt,
                            int K, int N) {
  __shared__ float tile[64][65];  // +1 pad: conflict-free column reads
  int e = blockIdx.z;
  const float* we = w + (size_t)e * K * N;
  u16* wte = wt + (size_t)e * K * N;
  int n0 = blockIdx.x * 64, k0 = blockIdx.y * 64;
  int t = threadIdx.x;
  int kl = t >> 4, n4 = (t & 15) * 4;
#pragma unroll
  for (int r = 0; r < 4; r++) {
    int k = r * 16 + kl;
    float4 v = *(const float4*)(we + (size_t)(k0 + k) * N + n0 + n4);
    tile[k][n4 + 0] = v.x; tile[k][n4 + 1] = v.y;
    tile[k][n4 + 2] = v.z; tile[k][n4 + 3] = v.w;
  }
  __syncthreads();
#pragma unroll
  for (int r = 0; r < 2; r++) {
    int c = r * 256 + t;
    int n = c >> 3, kc = (c & 7) * 8;
    us8 o;
#pragma unroll
    for (int j = 0; j < 8; j++) o[j] = f2bf(tile[kc + j][n]);
    *(us8*)(wte + (size_t)(n0 + n) * K + k0 + kc) = o;
  }
}

// fused gate+up transpose: z<kE -> w_gate, z>=kE -> w_up (same shape)
__global__ void transp_gu(const float* __restrict__ wgp, const float* __restrict__ wup,
                          u16* __restrict__ Wgt, u16* __restrict__ Wut) {
  __shared__ float tile[64][65];
  int z = blockIdx.z;
  int e = z & 7;
  const float* w = (z < kE) ? wgp : wup;
  u16* wt = (z < kE) ? Wgt : Wut;
  const int K = kHID, N = kINTER;
  const float* we = w + (size_t)e * K * N;
  u16* wte = wt + (size_t)e * K * N;
  int n0 = blockIdx.x * 64, k0 = blockIdx.y * 64;
  int t = threadIdx.x;
  int kl = t >> 4, n4 = (t & 15) * 4;
#pragma unroll
  for (int r = 0; r < 4; r++) {
    int k = r * 16 + kl;
    float4 v = *(const float4*)(we + (size_t)(k0 + k) * N + n0 + n4);
    tile[k][n4 + 0] = v.x; tile[k][n4 + 1] = v.y;
    tile[k][n4 + 2] = v.z; tile[k][n4 + 3] = v.w;
  }
  __syncthreads();
#pragma unroll
  for (int r = 0; r < 2; r++) {
    int c = r * 256 + t;
    int n = c >> 3, kc = (c & 7) * 8;
    us8 o;
#pragma unroll
    for (int j = 0; j < 8; j++) o[j] = f2bf(tile[kc + j][n]);
    *(us8*)(wte + (size_t)(n0 + n) * K + k0 + kc) = o;
  }
}

// -------- expert lookup: flat 256-row m-supertile -> (expert, row range) --------
static __device__ __forceinline__ bool expert_of_tile256(
    const int* __restrict__ tpe, int ty, int& e, int& m0, int& m_end) {
  int tile_base = 0, row_base = 0;
  e = -1;
  for (int i = 0; i < kE; i++) {
    int tc = tpe[i];
    int nt = (tc + 255) >> 8;
    if (e < 0 && ty < tile_base + nt) {
      e = i;
      m0 = row_base + (ty - tile_base) * 256;
      m_end = row_base + tc;
    }
    tile_base += nt;
    row_base += tc;
  }
  return e >= 0;
}

// -------- T1: bijective XCD chunking (m204) + GROUP-4 m-supertile decode --------
static __device__ __forceinline__ void map_block(int& bx, int& by) {
  int nx = gridDim.x, ny = gridDim.y;
  int nwg = nx * ny;
  int flat = blockIdx.y * nx + blockIdx.x;
  int q = nwg >> 3, r = nwg & 7;
  int xcd = flat & 7, lid = flat >> 3;
  int nf = (xcd < r ? xcd * (q + 1) : r * (q + 1) + (xcd - r) * q) + lid;
  const int G = 4;
  int gs = G * nx;
  int grp = nf / gs;
  int wi = nf - grp * gs;
  int rows = ny - grp * G;
  if (rows > G) rows = G;
  bx = wi / rows;
  by = grp * G + (wi - bx * rows);
}

// ---------------- GEMM1: 256x128 tile, BK=64, 8 waves (4Mx2N), gate+up fused ----------------
// LDS 128KB: double-buffered A(256x64) + Bg(128x64) + Bu(128x64), bf16.
// T2 swizzle: linear gll16 dest, pre-swizzled global source chunk, swizzled ds_read.
// VERIFIED round-1 kernel — unchanged.
__launch_bounds__(512, 2)
__global__ void gemm1(const u16* __restrict__ Xb, const u16* __restrict__ Wgt,
                      const u16* __restrict__ Wut, const float* __restrict__ probs,
                      const int* __restrict__ tpe, u16* __restrict__ H) {
  __shared__ __align__(16) u16 sm[65536];  // 128 KB
  u16* A0 = sm;           u16* A1 = sm + 16384;
  u16* Bg0 = sm + 32768;  u16* Bg1 = sm + 40960;
  u16* Bu0 = sm + 49152;  u16* Bu1 = sm + 57344;

  int bx, by; map_block(bx, by);
  int e, m0, m_end;
  if (!expert_of_tile256(tpe, by, e, m0, m_end)) return;
  int n0 = bx * 128;

  int t = threadIdx.x;
  int w = t >> 6, lane = t & 63;
  int quad = lane >> 4, l15 = lane & 15;
  int wm = (w >> 1) * 64, wn = (w & 1) * 64;

  // staging: per round 512 threads x 16B = 64 rows x 128B. row = r*64 + (t>>3).
  // swizzled source chunk keeps LDS dest linear (gll16 requirement).
  int trow = t >> 3;
  int cg = (t & 7) ^ (trow & 7);
  const u16* gA[4];
#pragma unroll
  for (int rr = 0; rr < 4; rr++) {
    int row = m0 + rr * 64 + trow;
    if (row > kTOT - 1) row = kTOT - 1;
    gA[rr] = Xb + (size_t)row * kHID + cg * 8;
  }
  const u16 *gBg[2], *gBu[2];
#pragma unroll
  for (int rr = 0; rr < 2; rr++) {
    size_t nrow = (size_t)e * kINTER + n0 + rr * 64 + trow;
    gBg[rr] = Wgt + nrow * kHID + cg * 8;
    gBu[rr] = Wut + nrow * kHID + cg * 8;
  }

  // ds_read offsets: row*64 + (chunk ^ (row&7))*8, chunk = ks*4+quad, row&7 == l15&7
  int abase = (wm + l15) * 64;
  int bbase = (wn + l15) * 64;
  int sz0 = ((quad ^ (l15 & 7)) << 3);
  int sz1 = (((4 | quad) ^ (l15 & 7)) << 3);

  f32x4 accg[4][4] = {};
  f32x4 accu[4][4] = {};

  auto stage = [&](u16* A, u16* Bg, u16* Bu, int ko) {
#pragma unroll
    for (int rr = 0; rr < 4; rr++) gll16(gA[rr] + ko, A + (rr * 64 + w * 8) * 64);
#pragma unroll
    for (int rr = 0; rr < 2; rr++) {
      gll16(gBg[rr] + ko, Bg + (rr * 64 + w * 8) * 64);
      gll16(gBu[rr] + ko, Bu + (rr * 64 + w * 8) * 64);
    }
  };
  auto compute = [&](const u16* A, const u16* Bg, const u16* Bu) {
#pragma unroll
    for (int ks = 0; ks < 2; ks++) {
      int sz = ks ? sz1 : sz0;
      bf16x8 a[4], bg[4], bu[4];
#pragma unroll
      for (int i = 0; i < 4; i++) a[i] = *(const bf16x8*)(A + abase + i * 1024 + sz);
#pragma unroll
      for (int j = 0; j < 4; j++) {
        bg[j] = *(const bf16x8*)(Bg + bbase + j * 1024 + sz);
        bu[j] = *(const bf16x8*)(Bu + bbase + j * 1024 + sz);
      }
#pragma unroll
      for (int i = 0; i < 4; i++)
#pragma unroll
        for (int j = 0; j < 4; j++) {
          accg[i][j] = __builtin_amdgcn_mfma_f32_16x16x32_bf16(a[i], bg[j], accg[i][j], 0, 0, 0);
          accu[i][j] = __builtin_amdgcn_mfma_f32_16x16x32_bf16(a[i], bu[j], accu[i][j], 0, 0, 0);
        }
    }
  };

  stage(A0, Bg0, Bu0, 0);
  __syncthreads();
  for (int kt = 0; kt < kHID / 64; kt += 2) {
    stage(A1, Bg1, Bu1, (kt + 1) * 64);   // prefetch overlaps compute below
    compute(A0, Bg0, Bu0);
    __syncthreads();
    if (kt + 2 < kHID / 64) stage(A0, Bg0, Bu0, (kt + 2) * 64);
    compute(A1, Bg1, Bu1);
    __syncthreads();
  }

  // epilogue: h = silu(gate)*up*prob[row]. C/D layout: col=l15, row=quad*4+reg
#pragma unroll
  for (int i = 0; i < 4; i++) {
#pragma unroll
    for (int r = 0; r < 4; r++) {
      int row = m0 + wm + i * 16 + quad * 4 + r;
      if (row < m_end) {
        float p = probs[row];
#pragma unroll
        for (int j = 0; j < 4; j++) {
          int col = n0 + wn + j * 16 + l15;
          float g = accg[i][j][r], u = accu[i][j][r];
          float s = g / (1.0f + __expf(-g));
          H[(size_t)row * kINTER + col] = f2bf(s * u * p);
        }
      }
    }
  }
}

// ---------------- GEMM2: 256x128 tile, BK=64, 8 waves (4Mx2N) ----------------
// Structural clone of verified gemm1 (one B operand, fp32 epilogue). LDS 96KB dbuf.
__launch_bounds__(512, 2)
__global__ void gemm2(const u16* __restrict__ H, const u16* __restrict__ Wdt,
                      const int* __restrict__ tpe, float* __restrict__ out) {
  __shared__ __align__(16) u16 sm[49152];  // 96 KB
  u16* A0 = sm;          u16* A1 = sm + 16384;   // 256x64 each
  u16* B0 = sm + 32768;  u16* B1 = sm + 40960;   // 128x64 each

  int bx, by; map_block(bx, by);
  int e, m0, m_end;
  if (!expert_of_tile256(tpe, by, e, m0, m_end)) return;
  int n0 = bx * 128;

  int t = threadIdx.x;
  int w = t >> 6, lane = t & 63;
  int quad = lane >> 4, l15 = lane & 15;
  int wm = (w >> 1) * 64, wn = (w & 1) * 64;

  int trow = t >> 3;
  int cg = (t & 7) ^ (trow & 7);
  const u16* gA[4];
#pragma unroll
  for (int rr = 0; rr < 4; rr++) {
    int row = m0 + rr * 64 + trow;
    if (row > kTOT - 1) row = kTOT - 1;
    gA[rr] = H + (size_t)row * kINTER + cg * 8;
  }
  const u16* gB[2];
#pragma unroll
  for (int rr = 0; rr < 2; rr++) {
    size_t nrow = (size_t)e * kHID + n0 + rr * 64 + trow;
    gB[rr] = Wdt + nrow * kINTER + cg * 8;
  }

  int abase = (wm + l15) * 64;
  int bbase = (wn + l15) * 64;
  int sz0 = ((quad ^ (l15 & 7)) << 3);
  int sz1 = (((4 | quad) ^ (l15 & 7)) << 3);

  f32x4 acc[4][4] = {};

  auto stage = [&](u16* A, u16* B, int ko) {
#pragma unroll
    for (int rr = 0; rr < 4; rr++) gll16(gA[rr] + ko, A + (rr * 64 + w * 8) * 64);
#pragma unroll
    for (int rr = 0; rr < 2; rr++) gll16(gB[rr] + ko, B + (rr * 64 + w * 8) * 64);
  };
  auto compute = [&](const u16* A, const u16* B) {
#pragma unroll
    for (int ks = 0; ks < 2; ks++) {
      int sz = ks ? sz1 : sz0;
      bf16x8 a[4], b[4];
#pragma unroll
      for (int i = 0; i < 4; i++) a[i] = *(const bf16x8*)(A + abase + i * 1024 + sz);
#pragma unroll
      for (int j = 0; j < 4; j++) b[j] = *(const bf16x8*)(B + bbase + j * 1024 + sz);
#pragma unroll
      for (int i = 0; i < 4; i++)
#pragma unroll
        for (int j = 0; j < 4; j++)
          acc[i][j] = __builtin_amdgcn_mfma_f32_16x16x32_bf16(a[i], b[j], acc[i][j], 0, 0, 0);
    }
  };

  stage(A0, B0, 0);
  __syncthreads();
  for (int kt = 0; kt < kINTER / 64; kt += 2) {
    stage(A1, B1, (kt + 1) * 64);
    compute(A0, B0);
    __syncthreads();
    if (kt + 2 < kINTER / 64) stage(A0, B0, (kt + 2) * 64);
    compute(A1, B1);
    __syncthreads();
  }

#pragma unroll
  for (int i = 0; i < 4; i++) {
#pragma unroll
    for (int r = 0; r < 4; r++) {
      int row = m0 + wm + i * 16 + quad * 4 + r;
      if (row < m_end) {
#pragma unroll
        for (int j = 0; j < 4; j++) {
          int col = n0 + wn + j * 16 + l15;
          out[(size_t)row * kHID + col] = acc[i][j][r];
        }
      }
    }
  }
}

extern "C" void kernel_launch(void* const* d_in, const int* in_sizes, int n_in,
                              void* d_out, int out_size, void* d_ws, size_t ws_size,
                              hipStream_t stream) {
  const float* x = (const float*)d_in[0];
  const float* probs = (const float*)d_in[1];
  const float* wg = (const float*)d_in[2];
  const float* wu = (const float*)d_in[3];
  const float* wd = (const float*)d_in[4];
  const int* tpe = (const int*)d_in[5];
  float* out = (float*)d_out;

  // ws layout (u16 elements): Xb | Wg_t | Wu_t | Wd_t | H  (~186 MB total)
  u16* ws = (u16*)d_ws;
  u16* Xb = ws;
  u16* Wgt = Xb + (size_t)kTOT * kHID;
  u16* Wut = Wgt + (size_t)kE * kINTER * kHID;
  u16* Wdt = Wut + (size_t)kE * kINTER * kHID;
  u16* H = Wdt + (size_t)kE * kHID * kINTER;

  conv_bf16<<<(kTOT * kHID) / (256 * 8), 256, 0, stream>>>(x, Xb);
  // fused: w_gate + w_up [E][HID][INTER] -> [E][INTER][HID]
  transp_gu<<<dim3(kINTER / 64, kHID / 64, 2 * kE), 256, 0, stream>>>(wg, wu, Wgt, Wut);
  // w_down: [E][INTER][HID] -> [E][HID][INTER]
  transp_bf16<<<dim3(kHID / 64, kINTER / 64, kE), 256, 0, stream>>>(wd, Wdt, kINTER, kHID);

  // 256-row supertiles: 32 full + up to 7 partials; extra blocks early-exit
  gemm1<<<dim3(kINTER / 128, 39), 512, 0, stream>>>(Xb, Wgt, Wut, probs, tpe, H);
  gemm2<<<dim3(kHID / 128, 39), 512, 0, stream>>>(H, Wdt, tpe, out);
}

// Round 4
// 532.375 us; speedup vs baseline: 1.0109x; 1.0109x over previous
//
#include <hip/hip_runtime.h>

typedef unsigned short u16;
typedef unsigned int u32;
typedef u16 us8 __attribute__((ext_vector_type(8)));
typedef __bf16 bf16x8 __attribute__((ext_vector_type(8)));
typedef float f32x4 __attribute__((ext_vector_type(4)));

constexpr int kE = 8;
constexpr int kHID = 2048;    // K of GEMM1, N of GEMM2
constexpr int kINTER = 1408;  // N of GEMM1, K of GEMM2
constexpr int kTOT = 8192;

// fp32 -> bf16 round-to-nearest-even
static __device__ __forceinline__ u16 f2bf(float f) {
  u32 u = __float_as_uint(f);
  u32 r = (u + 0x7fffu + ((u >> 16) & 1u)) >> 16;
  return (u16)r;
}

// async global->LDS; LDS dest = wave-uniform base, HW adds lane*16B
static __device__ __forceinline__ void gll16(const u16* g, u16* l) {
  __builtin_amdgcn_global_load_lds(
      (const __attribute__((address_space(1))) u32*)g,
      (__attribute__((address_space(3))) u32*)l, 16, 0, 0);
}

// ---------------- pre-pass: X fp32 -> bf16 ----------------
__global__ void conv_bf16(const float* __restrict__ x, u16* __restrict__ o) {
  size_t i = ((size_t)blockIdx.x * 256 + threadIdx.x) * 8;
  const float4* p = (const float4*)(x + i);
  float4 f0 = p[0], f1 = p[1];
  us8 v;
  v[0] = f2bf(f0.x); v[1] = f2bf(f0.y); v[2] = f2bf(f0.z); v[3] = f2bf(f0.w);
  v[4] = f2bf(f1.x); v[5] = f2bf(f1.y); v[6] = f2bf(f1.z); v[7] = f2bf(f1.w);
  *(us8*)(o + i) = v;
}

// ---------------- pre-pass: W[e][K][N] fp32 -> Wt[e][N][K] bf16 ----------------
__global__ void transp_bf16(const float* __restrict__ w, u16* __restrict__ wt,
                            int K, int N) {
  __shared__ float tile[64][65];  // +1 pad: conflict-free column reads
  int e = blockIdx.z;
  const float* we = w + (size_t)e * K * N;
  u16* wte = wt + (size_t)e * K * N;
  int n0 = blockIdx.x * 64, k0 = blockIdx.y * 64;
  int t = threadIdx.x;
  int kl = t >> 4, n4 = (t & 15) * 4;
#pragma unroll
  for (int r = 0; r < 4; r++) {
    int k = r * 16 + kl;
    float4 v = *(const float4*)(we + (size_t)(k0 + k) * N + n0 + n4);
    tile[k][n4 + 0] = v.x; tile[k][n4 + 1] = v.y;
    tile[k][n4 + 2] = v.z; tile[k][n4 + 3] = v.w;
  }
  __syncthreads();
#pragma unroll
  for (int r = 0; r < 2; r++) {
    int c = r * 256 + t;
    int n = c >> 3, kc = (c & 7) * 8;
    us8 o;
#pragma unroll
    for (int j = 0; j < 8; j++) o[j] = f2bf(tile[kc + j][n]);
    *(us8*)(wte + (size_t)(n0 + n) * K + k0 + kc) = o;
  }
}

// fused gate+up transpose: z<kE -> w_gate, z>=kE -> w_up (same shape)
__global__ void transp_gu(const float* __restrict__ wgp, const float* __restrict__ wup,
                          u16* __restrict__ Wgt, u16* __restrict__ Wut) {
  __shared__ float tile[64][65];
  int z = blockIdx.z;
  int e = z & 7;
  const float* w = (z < kE) ? wgp : wup;
  u16* wt = (z < kE) ? Wgt : Wut;
  const int K = kHID, N = kINTER;
  const float* we = w + (size_t)e * K * N;
  u16* wte = wt + (size_t)e * K * N;
  int n0 = blockIdx.x * 64, k0 = blockIdx.y * 64;
  int t = threadIdx.x;
  int kl = t >> 4, n4 = (t & 15) * 4;
#pragma unroll
  for (int r = 0; r < 4; r++) {
    int k = r * 16 + kl;
    float4 v = *(const float4*)(we + (size_t)(k0 + k) * N + n0 + n4);
    tile[k][n4 + 0] = v.x; tile[k][n4 + 1] = v.y;
    tile[k][n4 + 2] = v.z; tile[k][n4 + 3] = v.w;
  }
  __syncthreads();
#pragma unroll
  for (int r = 0; r < 2; r++) {
    int c = r * 256 + t;
    int n = c >> 3, kc = (c & 7) * 8;
    us8 o;
#pragma unroll
    for (int j = 0; j < 8; j++) o[j] = f2bf(tile[kc + j][n]);
    *(us8*)(wte + (size_t)(n0 + n) * K + k0 + kc) = o;
  }
}

// -------- expert lookup: flat 128-row m-tile -> (expert, row range) --------
static __device__ __forceinline__ bool expert_of_tile(
    const int* __restrict__ tpe, int ty, int& e, int& m0, int& m_end) {
  int tile_base = 0, row_base = 0;
  e = -1;
  for (int i = 0; i < kE; i++) {
    int tc = tpe[i];
    int nt = (tc + 127) >> 7;
    if (e < 0 && ty < tile_base + nt) {
      e = i;
      m0 = row_base + (ty - tile_base) * 128;
      m_end = row_base + tc;
    }
    tile_base += nt;
    row_base += tc;
  }
  return e >= 0;
}

// -------- T1: bijective XCD chunking (m204) + GROUP-4 m-tile decode --------
static __device__ __forceinline__ void map_block(int& bx, int& by) {
  int nx = gridDim.x, ny = gridDim.y;
  int nwg = nx * ny;
  int flat = blockIdx.y * nx + blockIdx.x;
  int q = nwg >> 3, r = nwg & 7;
  int xcd = flat & 7, lid = flat >> 3;
  int nf = (xcd < r ? xcd * (q + 1) : r * (q + 1) + (xcd - r) * q) + lid;
  const int G = 4;
  int gs = G * nx;
  int grp = nf / gs;
  int wi = nf - grp * gs;
  int rows = ny - grp * G;
  if (rows > G) rows = G;
  bx = wi / rows;
  by = grp * G + (wi - bx * rows);
}

// ---------------- GEMM1: 128x128 tile, BK=32, 8 waves (2Mx4N, wave 64x32), gate+up fused ----------
// LDS 48KB dbuf (A 8K | Bg 8K | Bu 8K per buffer) -> 2 blocks/CU; acc 64 f32/lane.
// Verified round-1 prefetch skeleton: stage(next) -> compute(cur) -> sync.
// Swizzle (BK=32, 64B rows): source chunk (t&3)^((t>>3)&3); read chunk quad^((l15>>1)&3) -> 2-way (free).
__launch_bounds__(512, 4)
__global__ void gemm1(const u16* __restrict__ Xb, const u16* __restrict__ Wgt,
                      const u16* __restrict__ Wut, const float* __restrict__ probs,
                      const int* __restrict__ tpe, u16* __restrict__ H) {
  __shared__ __align__(16) u16 sm[24576];  // 48 KB

  int bx, by; map_block(bx, by);
  int e, m0, m_end;
  if (!expert_of_tile(tpe, by, e, m0, m_end)) return;
  int n0 = bx * 128;

  int t = threadIdx.x;
  int w = t >> 6, lane = t & 63;
  int quad = lane >> 4, l15 = lane & 15;
  int wm = (w >> 2) * 64, wn = (w & 3) * 32;

  // staging: 512 threads x 16B = 8KB = one 128x32 bf16 panel per gll16 round.
  // thread t covers (row = t>>2, chunk slot = t&3); source chunk pre-swizzled.
  int trow = t >> 2;
  int cg = (t & 3) ^ ((t >> 3) & 3);
  int arow = m0 + trow; if (arow > kTOT - 1) arow = kTOT - 1;
  const u16* gA = Xb + (size_t)arow * kHID + cg * 8;
  size_t nrow = (size_t)e * kINTER + n0 + trow;
  const u16* gBg = Wgt + nrow * kHID + cg * 8;
  const u16* gBu = Wut + nrow * kHID + cg * 8;
  u16* dst = sm + w * 512;  // wave-uniform base; HW adds lane*16B

  // ds_read: row*32 + (quad ^ ((l15>>1)&3))*8
  int cs = ((l15 >> 1) & 3);
  int sz = ((quad ^ cs) << 3);
  int aoff[4], boff[2];
#pragma unroll
  for (int i = 0; i < 4; i++) aoff[i] = (wm + i * 16 + l15) * 32 + sz;
#pragma unroll
  for (int j = 0; j < 2; j++) boff[j] = (wn + j * 16 + l15) * 32 + sz;

  f32x4 accg[4][2] = {};
  f32x4 accu[4][2] = {};

  auto stage = [&](int buf, int ko) {
    u16* d = dst + buf * 12288;
    gll16(gA + ko, d);
    gll16(gBg + ko, d + 4096);
    gll16(gBu + ko, d + 8192);
  };
  auto compute = [&](int buf) {
    const u16* b = sm + buf * 12288;
    bf16x8 a[4], bg[2], bu[2];
#pragma unroll
    for (int i = 0; i < 4; i++) a[i] = *(const bf16x8*)(b + aoff[i]);
#pragma unroll
    for (int j = 0; j < 2; j++) {
      bg[j] = *(const bf16x8*)(b + 4096 + boff[j]);
      bu[j] = *(const bf16x8*)(b + 8192 + boff[j]);
    }
#pragma unroll
    for (int i = 0; i < 4; i++)
#pragma unroll
      for (int j = 0; j < 2; j++) {
        accg[i][j] = __builtin_amdgcn_mfma_f32_16x16x32_bf16(a[i], bg[j], accg[i][j], 0, 0, 0);
        accu[i][j] = __builtin_amdgcn_mfma_f32_16x16x32_bf16(a[i], bu[j], accu[i][j], 0, 0, 0);
      }
  };

  constexpr int NK = kHID / 32;  // 64, even
  stage(0, 0);
  __syncthreads();
  for (int kt = 0; kt < NK; kt += 2) {
    stage(1, (kt + 1) * 32);   // prefetch overlaps compute below
    compute(0);
    __syncthreads();
    if (kt + 2 < NK) stage(0, (kt + 2) * 32);
    compute(1);
    __syncthreads();
  }

  // epilogue: h = silu(gate)*up*prob[row]. C/D layout: col=l15, row=quad*4+reg
#pragma unroll
  for (int i = 0; i < 4; i++) {
#pragma unroll
    for (int r = 0; r < 4; r++) {
      int row = m0 + wm + i * 16 + quad * 4 + r;
      if (row < m_end) {
        float p = probs[row];
#pragma unroll
        for (int j = 0; j < 2; j++) {
          int col = n0 + wn + j * 16 + l15;
          float g = accg[i][j][r], u = accu[i][j][r];
          float s = g / (1.0f + __expf(-g));
          H[(size_t)row * kINTER + col] = f2bf(s * u * p);
        }
      }
    }
  }
}

// ---------------- GEMM2: 128x128 tile, BK=32, 8 waves (2Mx4N, wave 64x32) ----------------
// LDS 32KB dbuf -> 2-3 blocks/CU; acc 32 f32/lane.
__launch_bounds__(512, 4)
__global__ void gemm2(const u16* __restrict__ H, const u16* __restrict__ Wdt,
                      const int* __restrict__ tpe, float* __restrict__ out) {
  __shared__ __align__(16) u16 sm[16384];  // 32 KB

  int bx, by; map_block(bx, by);
  int e, m0, m_end;
  if (!expert_of_tile(tpe, by, e, m0, m_end)) return;
  int n0 = bx * 128;

  int t = threadIdx.x;
  int w = t >> 6, lane = t & 63;
  int quad = lane >> 4, l15 = lane & 15;
  int wm = (w >> 2) * 64, wn = (w & 3) * 32;

  int trow = t >> 2;
  int cg = (t & 3) ^ ((t >> 3) & 3);
  int arow = m0 + trow; if (arow > kTOT - 1) arow = kTOT - 1;
  const u16* gA = H + (size_t)arow * kINTER + cg * 8;
  size_t nrow = (size_t)e * kHID + n0 + trow;
  const u16* gB = Wdt + nrow * kINTER + cg * 8;
  u16* dst = sm + w * 512;

  int cs = ((l15 >> 1) & 3);
  int sz = ((quad ^ cs) << 3);
  int aoff[4], boff[2];
#pragma unroll
  for (int i = 0; i < 4; i++) aoff[i] = (wm + i * 16 + l15) * 32 + sz;
#pragma unroll
  for (int j = 0; j < 2; j++) boff[j] = (wn + j * 16 + l15) * 32 + sz;

  f32x4 acc[4][2] = {};

  auto stage = [&](int buf, int ko) {
    u16* d = dst + buf * 8192;
    gll16(gA + ko, d);
    gll16(gB + ko, d + 4096);
  };
  auto compute = [&](int buf) {
    const u16* b = sm + buf * 8192;
    bf16x8 a[4], bb[2];
#pragma unroll
    for (int i = 0; i < 4; i++) a[i] = *(const bf16x8*)(b + aoff[i]);
#pragma unroll
    for (int j = 0; j < 2; j++) bb[j] = *(const bf16x8*)(b + 4096 + boff[j]);
#pragma unroll
    for (int i = 0; i < 4; i++)
#pragma unroll
      for (int j = 0; j < 2; j++)
        acc[i][j] = __builtin_amdgcn_mfma_f32_16x16x32_bf16(a[i], bb[j], acc[i][j], 0, 0, 0);
  };

  constexpr int NK = kINTER / 32;  // 44, even
  stage(0, 0);
  __syncthreads();
  for (int kt = 0; kt < NK; kt += 2) {
    stage(1, (kt + 1) * 32);
    compute(0);
    __syncthreads();
    if (kt + 2 < NK) stage(0, (kt + 2) * 32);
    compute(1);
    __syncthreads();
  }

#pragma unroll
  for (int i = 0; i < 4; i++) {
#pragma unroll
    for (int r = 0; r < 4; r++) {
      int row = m0 + wm + i * 16 + quad * 4 + r;
      if (row < m_end) {
#pragma unroll
        for (int j = 0; j < 2; j++) {
          int col = n0 + wn + j * 16 + l15;
          out[(size_t)row * kHID + col] = acc[i][j][r];
        }
      }
    }
  }
}

extern "C" void kernel_launch(void* const* d_in, const int* in_sizes, int n_in,
                              void* d_out, int out_size, void* d_ws, size_t ws_size,
                              hipStream_t stream) {
  const float* x = (const float*)d_in[0];
  const float* probs = (const float*)d_in[1];
  const float* wg = (const float*)d_in[2];
  const float* wu = (const float*)d_in[3];
  const float* wd = (const float*)d_in[4];
  const int* tpe = (const int*)d_in[5];
  float* out = (float*)d_out;

  // ws layout (u16 elements): Xb | Wg_t | Wu_t | Wd_t | H  (~186 MB total)
  u16* ws = (u16*)d_ws;
  u16* Xb = ws;
  u16* Wgt = Xb + (size_t)kTOT * kHID;
  u16* Wut = Wgt + (size_t)kE * kINTER * kHID;
  u16* Wdt = Wut + (size_t)kE * kINTER * kHID;
  u16* H = Wdt + (size_t)kE * kHID * kINTER;

  conv_bf16<<<(kTOT * kHID) / (256 * 8), 256, 0, stream>>>(x, Xb);
  // fused: w_gate + w_up [E][HID][INTER] -> [E][INTER][HID]
  transp_gu<<<dim3(kINTER / 64, kHID / 64, 2 * kE), 256, 0, stream>>>(wg, wu, Wgt, Wut);
  // w_down: [E][INTER][HID] -> [E][HID][INTER]
  transp_bf16<<<dim3(kHID / 64, kINTER / 64, kE), 256, 0, stream>>>(wd, Wdt, kINTER, kHID);

  // 128-row m-tiles: 64 full (all expert counts are multiples of 128); extra blocks early-exit
  gemm1<<<dim3(kINTER / 128, 72), 512, 0, stream>>>(Xb, Wgt, Wut, probs, tpe, H);
  gemm2<<<dim3(kHID / 128, 72), 512, 0, stream>>>(H, Wdt, tpe, out);
}